// Round 3
// baseline (139.491 us; speedup 1.0000x reference)
//
#include <hip/hip_runtime.h>
#include <hip/hip_cooperative_groups.h>
#include <math.h>

namespace cg = cooperative_groups;

#define BB 4
#define NN 512
#define F_IN 256
#define F_OUT 128
#define HH 64
#define NEG_INF_F -1e30f
#define LALPHA 0.01f

// ============================================================================
// Fused cooperative kernel: 256 blocks x 512 threads, 8 i-rows per block.
// ============================================================================
__global__ __launch_bounds__(512, 2) void k_gat(
    const float* __restrict__ x, const float* __restrict__ adj,
    const float* __restrict__ W, const float* __restrict__ bW,
    const float* __restrict__ A1, const float* __restrict__ b1,
    const float* __restrict__ A2, const float* __restrict__ b2,
    float* __restrict__ h, float* __restrict__ hjT,
    float* __restrict__ stat_m, float* __restrict__ stat_s,
    float* __restrict__ out)
{
    cg::grid_group grid = cg::this_grid();
    const int blk  = blockIdx.x;        // 0..255
    const int b    = blk >> 6;          // 64 blocks per batch
    const int i0l  = (blk & 63) * 8;    // local row in batch
    const int row0 = b * NN + i0l;      // global row
    const int tid  = threadIdx.x;

    __shared__ float xs[8 * F_IN];        // 8 KB   (phase 0)
    __shared__ float hs[8 * F_OUT];       // 4 KB   (phase 0)
    __shared__ float hjs[8 * HH];         // 2 KB   (phase 0)
    __shared__ float hib[8 * HH];         // 2 KB   (phase 0 -> 1)  hi + b1
    __shared__ float a2s[HH];             // 256 B
    __shared__ float e_lds[NN][8];        // 16 KB  (phase 1 -> 2)  exp'd weights
    __shared__ float red[4][8][F_OUT];    // 16 KB  (phase 0 & 2 scratch)
    __shared__ float rtmp[16];

    // ---------------- Phase 0: projections ----------------
    #pragma unroll
    for (int t = 0; t < 4; ++t)
        xs[tid + t * 512] = x[(size_t)row0 * F_IN + tid + t * 512];
    if (tid < HH) a2s[tid] = A2[tid];
    __syncthreads();

    // h = x @ W^T : thread = (o = tid&127, f-quarter = tid>>7)
    {
        const int o  = tid & 127;
        const int fq = tid >> 7;
        float acc[8] = {0, 0, 0, 0, 0, 0, 0, 0};
        const float4* wr = (const float4*)(W + (size_t)o * F_IN + fq * 64);
        #pragma unroll 4
        for (int it = 0; it < 16; ++it) {
            const float4 wv = wr[it];
            #pragma unroll
            for (int r = 0; r < 8; ++r) {
                const float4 xv = *((const float4*)(xs + r * F_IN + fq * 64) + it);
                acc[r] = fmaf(xv.x, wv.x, acc[r]);
                acc[r] = fmaf(xv.y, wv.y, acc[r]);
                acc[r] = fmaf(xv.z, wv.z, acc[r]);
                acc[r] = fmaf(xv.w, wv.w, acc[r]);
            }
        }
        #pragma unroll
        for (int r = 0; r < 8; ++r) red[fq][r][o] = acc[r];
    }
    __syncthreads();
    #pragma unroll
    for (int s = 0; s < 2; ++s) {
        const int idx = tid + s * 512;      // 1024 = 8 rows x 128 o
        const int r = idx >> 7, o = idx & 127;
        const float v = red[0][r][o] + red[1][r][o] + red[2][r][o] + red[3][r][o] + bW[o];
        h[((size_t)row0 + r) * F_OUT + o] = v;
        hs[r * F_OUT + o] = v;
    }
    __syncthreads();

    // hi+b1 / hj : thread = (kh = tid&127 -> (k, half), o-quarter = tid>>7)
    {
        const int kh = tid & 127;
        const int k = kh & 63, half = kh >> 6;
        const int oq = tid >> 7;
        float acc[8] = {0, 0, 0, 0, 0, 0, 0, 0};
        const float4* ar = (const float4*)(A1 + (size_t)k * (2 * F_OUT) + half * F_OUT + oq * 32);
        #pragma unroll
        for (int it = 0; it < 8; ++it) {
            const float4 av = ar[it];
            #pragma unroll
            for (int r = 0; r < 8; ++r) {
                const float4 hv = *((const float4*)(hs + r * F_OUT + oq * 32) + it);
                acc[r] = fmaf(hv.x, av.x, acc[r]);
                acc[r] = fmaf(hv.y, av.y, acc[r]);
                acc[r] = fmaf(hv.z, av.z, acc[r]);
                acc[r] = fmaf(hv.w, av.w, acc[r]);
            }
        }
        __syncthreads();   // red free (h-part done)
        #pragma unroll
        for (int r = 0; r < 8; ++r) red[oq][r][kh] = acc[r];
    }
    __syncthreads();
    #pragma unroll
    for (int s = 0; s < 2; ++s) {
        const int idx = tid + s * 512;      // 1024 = 8 rows x 128 kh
        const int r = idx >> 7, kh = idx & 127;
        const float v = red[0][r][kh] + red[1][r][kh] + red[2][r][kh] + red[3][r][kh];
        if (kh < 64) hib[r * HH + kh] = v + b1[kh];
        else         hjs[r * HH + (kh - 64)] = v;
    }
    __syncthreads();
    {   // transposed store hjT[b][k][i0l + r]
        const int kk = tid >> 3, rr = tid & 7;
        hjT[((size_t)b * HH + kk) * NN + i0l + rr] = hjs[rr * HH + kk];
    }

    grid.sync();   // hjT, h visible to all blocks

    // ---------------- Phase 1: scores + per-block softmax stats ----------------
    const int j = tid;
    float adjv[8];
    #pragma unroll
    for (int r = 0; r < 8; ++r)
        adjv[r] = adj[((size_t)(b * NN) + i0l + r) * NN + j];
    const float b2v = b2[0];

    float s8[8] = {0, 0, 0, 0, 0, 0, 0, 0};
    const float* hjb = hjT + (size_t)b * HH * NN + j;
    #pragma unroll 2
    for (int k4 = 0; k4 < 16; ++k4) {
        const float hj0 = hjb[(size_t)(k4 * 4 + 0) * NN];
        const float hj1 = hjb[(size_t)(k4 * 4 + 1) * NN];
        const float hj2 = hjb[(size_t)(k4 * 4 + 2) * NN];
        const float hj3 = hjb[(size_t)(k4 * 4 + 3) * NN];
        const float4 a2v = *(const float4*)(a2s + k4 * 4);
        #pragma unroll
        for (int r = 0; r < 8; ++r) {
            const float4 hv = *(const float4*)(hib + r * HH + k4 * 4);
            s8[r] = fmaf(fmaxf(hv.x + hj0, 0.0f), a2v.x, s8[r]);
            s8[r] = fmaf(fmaxf(hv.y + hj1, 0.0f), a2v.y, s8[r]);
            s8[r] = fmaf(fmaxf(hv.z + hj2, 0.0f), a2v.z, s8[r]);
            s8[r] = fmaf(fmaxf(hv.w + hj3, 0.0f), a2v.w, s8[r]);
        }
    }

    float lmax = -INFINITY;
    #pragma unroll
    for (int r = 0; r < 8; ++r) {
        float v = s8[r] + b2v;
        v = (v >= 0.0f) ? v : LALPHA * v;
        v = (adjv[r] != 0.0f) ? v : NEG_INF_F;
        s8[r] = v;
        lmax = fmaxf(lmax, v);
    }

    // block max
    #pragma unroll
    for (int off = 32; off; off >>= 1) lmax = fmaxf(lmax, __shfl_xor(lmax, off, 64));
    if ((tid & 63) == 0) rtmp[tid >> 6] = lmax;
    __syncthreads();
    float m_blk = rtmp[0];
    #pragma unroll
    for (int w = 1; w < 8; ++w) m_blk = fmaxf(m_blk, rtmp[w]);
    __syncthreads();

    // exp + block sum; exp'd weights -> LDS
    float ls = 0.0f;
    #pragma unroll
    for (int r = 0; r < 8; ++r) {
        const float wv = expf(s8[r] - m_blk);
        e_lds[j][r] = wv;
        ls += wv;
    }
    #pragma unroll
    for (int off = 32; off; off >>= 1) ls += __shfl_xor(ls, off, 64);
    if ((tid & 63) == 0) rtmp[8 + (tid >> 6)] = ls;
    __syncthreads();
    if (tid == 0) {
        stat_m[blk] = m_blk;
        stat_s[blk] = rtmp[8] + rtmp[9] + rtmp[10] + rtmp[11] +
                      rtmp[12] + rtmp[13] + rtmp[14] + rtmp[15];
    }
    __threadfence();

    grid.sync();   // all stats visible

    // ---------------- Phase 1.5: batch-global M, S (redundant per block) ------
    __syncthreads();
    if (tid < 64) {
        const float m_i = stat_m[b * 64 + tid];
        const float s_i = stat_s[b * 64 + tid];
        float mm = m_i;
        #pragma unroll
        for (int off = 32; off; off >>= 1) mm = fmaxf(mm, __shfl_xor(mm, off, 64));
        float pp = s_i * expf(m_i - mm);
        #pragma unroll
        for (int off = 32; off; off >>= 1) pp += __shfl_xor(pp, off, 64);
        if (tid == 0) { rtmp[0] = mm; rtmp[1] = pp; }
    }
    __syncthreads();
    const float scale = expf(m_blk - rtmp[0]) / rtmp[1];

    // ---------------- Phase 2: aggregate + elu ----------------
    {
        const int o = tid & 127;
        const int p = tid >> 7;
        float acc[8] = {0, 0, 0, 0, 0, 0, 0, 0};
        const float* hb = h + (size_t)b * NN * F_OUT;
        #pragma unroll 4
        for (int jj = 0; jj < 128; ++jj) {
            const int jc = p * 128 + jj;
            const float hv = hb[(size_t)jc * F_OUT + o];
            const float4 w0 = *(const float4*)&e_lds[jc][0];
            const float4 w1 = *(const float4*)&e_lds[jc][4];
            acc[0] = fmaf(w0.x, hv, acc[0]);
            acc[1] = fmaf(w0.y, hv, acc[1]);
            acc[2] = fmaf(w0.z, hv, acc[2]);
            acc[3] = fmaf(w0.w, hv, acc[3]);
            acc[4] = fmaf(w1.x, hv, acc[4]);
            acc[5] = fmaf(w1.y, hv, acc[5]);
            acc[6] = fmaf(w1.z, hv, acc[6]);
            acc[7] = fmaf(w1.w, hv, acc[7]);
        }
        #pragma unroll
        for (int r = 0; r < 8; ++r) red[p][r][o] = acc[r];
    }
    __syncthreads();
    #pragma unroll
    for (int s = 0; s < 2; ++s) {
        const int idx = tid + s * 512;
        const int r = idx >> 7, oo = idx & 127;
        float v = (red[0][r][oo] + red[1][r][oo] + red[2][r][oo] + red[3][r][oo]) * scale;
        out[((size_t)(b * NN) + i0l + r) * F_OUT + oo] = (v > 0.0f) ? v : expm1f(v);
    }
}

// ============================================================================
// Fallback path (round-2 kernels, proven) — used if cooperative launch fails
// ============================================================================
__global__ __launch_bounds__(256) void k_proj(
    const float* __restrict__ x, const float* __restrict__ W,
    const float* __restrict__ bW, const float* __restrict__ A1,
    const float* __restrict__ b1,
    float* __restrict__ h, float* __restrict__ hi, float* __restrict__ hjT)
{
    const int row0 = blockIdx.x * 8;
    const int b    = row0 >> 9;
    const int rl0  = row0 & 511;
    const int tid  = threadIdx.x;

    __shared__ float xs[8 * F_IN];
    __shared__ float hs[8 * F_OUT];
    __shared__ float hjs[8 * HH];

    #pragma unroll
    for (int t = 0; t < 8; ++t)
        xs[tid + t * 256] = x[(size_t)row0 * F_IN + tid + t * 256];
    __syncthreads();

    {
        const int o  = tid & 127;
        const int rh = (tid >> 7) * 4;
        float acc[4];
        const float bv = bW[o];
        #pragma unroll
        for (int r = 0; r < 4; ++r) acc[r] = bv;
        const float4* wr = (const float4*)(W + (size_t)o * F_IN);
        #pragma unroll 4
        for (int f4 = 0; f4 < F_IN / 4; ++f4) {
            const float4 wv = wr[f4];
            #pragma unroll
            for (int r = 0; r < 4; ++r) {
                const float4 xv = *((const float4*)(xs + (rh + r) * F_IN) + f4);
                acc[r] = fmaf(xv.x, wv.x, acc[r]);
                acc[r] = fmaf(xv.y, wv.y, acc[r]);
                acc[r] = fmaf(xv.z, wv.z, acc[r]);
                acc[r] = fmaf(xv.w, wv.w, acc[r]);
            }
        }
        #pragma unroll
        for (int r = 0; r < 4; ++r) {
            h[((size_t)row0 + rh + r) * F_OUT + o] = acc[r];
            hs[(rh + r) * F_OUT + o] = acc[r];
        }
    }
    __syncthreads();

    {
        const int k    = tid & 63;
        const int half = (tid >> 6) & 1;
        const int rh   = (tid >> 7) * 4;
        float acc2[4];
        const float init = half ? 0.0f : b1[k];
        #pragma unroll
        for (int r = 0; r < 4; ++r) acc2[r] = init;
        const float4* ar = (const float4*)(A1 + (size_t)k * (2 * F_OUT) + half * F_OUT);
        #pragma unroll 4
        for (int o4 = 0; o4 < F_OUT / 4; ++o4) {
            const float4 av = ar[o4];
            #pragma unroll
            for (int r = 0; r < 4; ++r) {
                const float4 hv = *((const float4*)(hs + (rh + r) * F_OUT) + o4);
                acc2[r] = fmaf(hv.x, av.x, acc2[r]);
                acc2[r] = fmaf(hv.y, av.y, acc2[r]);
                acc2[r] = fmaf(hv.z, av.z, acc2[r]);
                acc2[r] = fmaf(hv.w, av.w, acc2[r]);
            }
        }
        if (half == 0) {
            #pragma unroll
            for (int r = 0; r < 4; ++r) hi[((size_t)row0 + rh + r) * HH + k] = acc2[r];
        } else {
            #pragma unroll
            for (int r = 0; r < 4; ++r) hjs[(rh + r) * HH + k] = acc2[r];
        }
    }
    __syncthreads();

    {
        const int kk = tid >> 2;
        const int r0 = (tid & 3) * 2;
        float2 v;
        v.x = hjs[(r0 + 0) * HH + kk];
        v.y = hjs[(r0 + 1) * HH + kk];
        *(float2*)(hjT + ((size_t)b * HH + kk) * NN + rl0 + r0) = v;
    }
}

__global__ __launch_bounds__(256) void k_scores(
    const float* __restrict__ hi, const float* __restrict__ hjT,
    const float* __restrict__ A2, const float* __restrict__ b2,
    const float* __restrict__ adj, float* __restrict__ e,
    float* __restrict__ stat_m, float* __restrict__ stat_s)
{
    const int blk = blockIdx.x;
    const int b   = blk >> 7;
    const int it  = (blk >> 1) & 63;
    const int i0  = it * 8;
    const int j   = (blk & 1) * 256 + threadIdx.x;
    const int tid = threadIdx.x;

    __shared__ float hib[8 * HH];
    __shared__ float a2s[HH];
    __shared__ float wred[4];

    hib[tid]       = hi[((size_t)(b * NN) + i0) * HH + tid];
    hib[tid + 256] = hi[((size_t)(b * NN) + i0) * HH + tid + 256];
    if (tid < HH) a2s[tid] = A2[tid];
    __syncthreads();

    float s[8] = {0, 0, 0, 0, 0, 0, 0, 0};
    const float* hjb = hjT + (size_t)b * HH * NN;
    #pragma unroll 4
    for (int k4 = 0; k4 < HH; k4 += 4) {
        const float hj0 = hjb[(size_t)(k4 + 0) * NN + j];
        const float hj1 = hjb[(size_t)(k4 + 1) * NN + j];
        const float hj2 = hjb[(size_t)(k4 + 2) * NN + j];
        const float hj3 = hjb[(size_t)(k4 + 3) * NN + j];
        const float4 a2v = *(const float4*)(a2s + k4);
        #pragma unroll
        for (int r = 0; r < 8; ++r) {
            const float4 hv = *(const float4*)(hib + r * HH + k4);
            s[r] = fmaf(fmaxf(hv.x + hj0, 0.0f), a2v.x, s[r]);
            s[r] = fmaf(fmaxf(hv.y + hj1, 0.0f), a2v.y, s[r]);
            s[r] = fmaf(fmaxf(hv.z + hj2, 0.0f), a2v.z, s[r]);
            s[r] = fmaf(fmaxf(hv.w + hj3, 0.0f), a2v.w, s[r]);
        }
    }

    const float b2v = b2[0];
    float lmax = -INFINITY;
    #pragma unroll
    for (int r = 0; r < 8; ++r) {
        float v = s[r] + b2v;
        v = (v >= 0.0f) ? v : LALPHA * v;
        const float a = adj[((size_t)(b * NN) + i0 + r) * NN + j];
        v = (a != 0.0f) ? v : NEG_INF_F;
        e[((size_t)(b * NN) + i0 + r) * NN + j] = v;
        s[r] = v;
        lmax = fmaxf(lmax, v);
    }

    float wm = lmax;
    #pragma unroll
    for (int off = 32; off; off >>= 1) wm = fmaxf(wm, __shfl_xor(wm, off, 64));
    if ((tid & 63) == 0) wred[tid >> 6] = wm;
    __syncthreads();
    const float m_blk = fmaxf(fmaxf(wred[0], wred[1]), fmaxf(wred[2], wred[3]));
    __syncthreads();

    float ls = 0.0f;
    #pragma unroll
    for (int r = 0; r < 8; ++r) ls += expf(s[r] - m_blk);
    #pragma unroll
    for (int off = 32; off; off >>= 1) ls += __shfl_xor(ls, off, 64);
    if ((tid & 63) == 0) wred[tid >> 6] = ls;
    __syncthreads();
    if (tid == 0) {
        stat_m[blk] = m_blk;
        stat_s[blk] = wred[0] + wred[1] + wred[2] + wred[3];
    }
}

__global__ __launch_bounds__(128) void k_reduce(
    const float* __restrict__ stat_m, const float* __restrict__ stat_s,
    float* __restrict__ Mg, float* __restrict__ Sg)
{
    const int b   = blockIdx.x;
    const int tid = threadIdx.x;
    __shared__ float sm[2], ss[2];

    const float m = stat_m[b * 128 + tid];
    float lm = m;
    #pragma unroll
    for (int off = 32; off; off >>= 1) lm = fmaxf(lm, __shfl_xor(lm, off, 64));
    if ((tid & 63) == 0) sm[tid >> 6] = lm;
    __syncthreads();
    const float M = fmaxf(sm[0], sm[1]);

    float sv = stat_s[b * 128 + tid] * expf(m - M);
    #pragma unroll
    for (int off = 32; off; off >>= 1) sv += __shfl_xor(sv, off, 64);
    if ((tid & 63) == 0) ss[tid >> 6] = sv;
    __syncthreads();
    if (tid == 0) { Mg[b] = M; Sg[b] = ss[0] + ss[1]; }
}

__global__ __launch_bounds__(512) void k_aggregate(
    const float* __restrict__ e, const float* __restrict__ h,
    const float* __restrict__ Mg, const float* __restrict__ Sg,
    float* __restrict__ out)
{
    const int blk = blockIdx.x;
    const int b   = blk >> 6;
    const int i0  = (blk & 63) * 8;
    const int tid = threadIdx.x;
    const int o   = tid & 127;
    const int p   = tid >> 7;

    const float M    = Mg[b];
    const float invS = 1.0f / Sg[b];

    __shared__ float wlsT[64][12];
    __shared__ float red[4][8][F_OUT];

    float acc[8] = {0, 0, 0, 0, 0, 0, 0, 0};
    const float* eb = e + ((size_t)(b * NN) + i0) * NN;
    const float* hb = h + (size_t)b * NN * F_OUT;

    for (int j0 = 0; j0 < NN; j0 += 64) {
        {
            const int jj = tid & 63, r = tid >> 6;
            wlsT[jj][r] = expf(eb[(size_t)r * NN + j0 + jj] - M);
        }
        __syncthreads();
        for (int jj = p; jj < 64; jj += 4) {
            const float hv = hb[(size_t)(j0 + jj) * F_OUT + o];
            const float4 w0 = *(const float4*)&wlsT[jj][0];
            const float4 w1 = *(const float4*)&wlsT[jj][4];
            acc[0] = fmaf(w0.x, hv, acc[0]);
            acc[1] = fmaf(w0.y, hv, acc[1]);
            acc[2] = fmaf(w0.z, hv, acc[2]);
            acc[3] = fmaf(w0.w, hv, acc[3]);
            acc[4] = fmaf(w1.x, hv, acc[4]);
            acc[5] = fmaf(w1.y, hv, acc[5]);
            acc[6] = fmaf(w1.z, hv, acc[6]);
            acc[7] = fmaf(w1.w, hv, acc[7]);
        }
        __syncthreads();
    }

    #pragma unroll
    for (int r = 0; r < 8; ++r) red[p][r][o] = acc[r];
    __syncthreads();
    #pragma unroll
    for (int t = 0; t < 2; ++t) {
        const int idx = tid + t * 512;
        const int r = idx >> 7, oo = idx & 127;
        float sv = red[0][r][oo] + red[1][r][oo] + red[2][r][oo] + red[3][r][oo];
        sv *= invS;
        out[((size_t)(b * NN) + i0 + r) * F_OUT + oo] = (sv > 0.0f) ? sv : expm1f(sv);
    }
}

extern "C" void kernel_launch(void* const* d_in, const int* in_sizes, int n_in,
                              void* d_out, int out_size, void* d_ws, size_t ws_size,
                              hipStream_t stream) {
    const float* x   = (const float*)d_in[0];
    const float* adj = (const float*)d_in[1];
    const float* W   = (const float*)d_in[2];
    const float* bW  = (const float*)d_in[3];
    const float* A1  = (const float*)d_in[4];
    const float* b1  = (const float*)d_in[5];
    const float* A2  = (const float*)d_in[6];
    const float* b2  = (const float*)d_in[7];
    float* out = (float*)d_out;

    float* ws  = (float*)d_ws;
    float* h      = ws;                                   // 262144
    float* hi     = h   + (size_t)BB * NN * F_OUT;        // 131072
    float* hjT    = hi  + (size_t)BB * NN * HH;           // 131072
    float* e      = hjT + (size_t)BB * HH * NN;           // 1048576
    float* stat_m = e   + (size_t)BB * NN * NN;           // 512
    float* stat_s = stat_m + 512;                         // 512
    float* Mg     = stat_s + 512;                         // 4
    float* Sg     = Mg + 4;                               // 4
    float* cstat_m = Sg + 4;                              // 256
    float* cstat_s = cstat_m + 256;                       // 256

    // Try the fused cooperative kernel first.
    void* args[] = { (void*)&x, (void*)&adj, (void*)&W, (void*)&bW,
                     (void*)&A1, (void*)&b1, (void*)&A2, (void*)&b2,
                     (void*)&h, (void*)&hjT, (void*)&cstat_m, (void*)&cstat_s,
                     (void*)&out };
    hipError_t rc = hipLaunchCooperativeKernel((void*)k_gat, dim3(BB * 64), dim3(512),
                                               args, 0, stream);
    if (rc == hipSuccess) return;

    // Fallback: proven 4-kernel pipeline.
    k_proj     <<<BB * 64,      256, 0, stream>>>(x, W, bW, A1, b1, h, hi, hjT);
    k_scores   <<<BB * 64 * 2,  256, 0, stream>>>(hi, hjT, A2, b2, adj, e, stat_m, stat_s);
    k_reduce   <<<BB,           128, 0, stream>>>(stat_m, stat_s, Mg, Sg);
    k_aggregate<<<BB * 64,      512, 0, stream>>>(e, h, Mg, Sg, out);
}

// Round 4
// 39.455 us; speedup vs baseline: 3.5355x; 3.5355x over previous
//
#include <hip/hip_runtime.h>
#include <math.h>

#define BB 4
#define NN 512
#define F_IN 256
#define F_OUT 128
#define HH 64
#define NEG_INF_F -1e30f
#define LALPHA 0.01f

// ============================================================================
// K1: h = x@W^T + bW ; hi = h@A1a^T + b1 ; hjT[b][k][n] = (h@A1b^T)^T
// 4 rows per block, 512 blocks x 256 threads, K-split + LDS reduce
// ============================================================================
__global__ __launch_bounds__(256) void k_proj(
    const float* __restrict__ x, const float* __restrict__ W,
    const float* __restrict__ bW, const float* __restrict__ A1,
    const float* __restrict__ b1,
    float* __restrict__ h, float* __restrict__ hi, float* __restrict__ hjT)
{
    const int row0 = blockIdx.x * 4;     // global row (b*N + n)
    const int b    = row0 >> 9;
    const int nl0  = row0 & 511;
    const int tid  = threadIdx.x;

    __shared__ float xs[4 * F_IN];           // 4 KB
    __shared__ float hs[4 * F_OUT];          // 2 KB
    __shared__ float hjs[4 * HH];            // 1 KB
    __shared__ float red[2][4][F_OUT];       // 4 KB

    #pragma unroll
    for (int t = 0; t < 4; ++t)
        xs[tid + t * 256] = x[(size_t)row0 * F_IN + tid + t * 256];
    __syncthreads();

    // ---- h: thread = (o = tid&127, K-half = tid>>7), 4 rows each ----
    {
        const int o  = tid & 127;
        const int kh = tid >> 7;
        float acc[4] = {0, 0, 0, 0};
        const float4* wr = (const float4*)(W + (size_t)o * F_IN + kh * 128);
        #pragma unroll 4
        for (int it = 0; it < 32; ++it) {
            const float4 wv = wr[it];
            #pragma unroll
            for (int r = 0; r < 4; ++r) {
                const float4 xv = *((const float4*)(xs + r * F_IN + kh * 128) + it);
                acc[r] = fmaf(xv.x, wv.x, acc[r]);
                acc[r] = fmaf(xv.y, wv.y, acc[r]);
                acc[r] = fmaf(xv.z, wv.z, acc[r]);
                acc[r] = fmaf(xv.w, wv.w, acc[r]);
            }
        }
        #pragma unroll
        for (int r = 0; r < 4; ++r) red[kh][r][o] = acc[r];
    }
    __syncthreads();
    #pragma unroll
    for (int t = 0; t < 2; ++t) {
        const int idx = tid + t * 256;      // 512 = 4 rows x 128 o
        const int r = idx >> 7, o = idx & 127;
        const float v = red[0][r][o] + red[1][r][o] + bW[o];
        h[((size_t)row0 + r) * F_OUT + o] = v;
        hs[r * F_OUT + o] = v;
    }
    __syncthreads();

    // ---- hi+b1 / hj : thread = (kh2 = tid&127 -> (k,half), O-half = tid>>7) ----
    {
        const int kh2  = tid & 127;
        const int k    = kh2 & 63, half = kh2 >> 6;
        const int oh   = tid >> 7;
        float acc[4] = {0, 0, 0, 0};
        const float4* ar = (const float4*)(A1 + (size_t)k * (2 * F_OUT) + half * F_OUT + oh * 64);
        #pragma unroll 4
        for (int it = 0; it < 16; ++it) {
            const float4 av = ar[it];
            #pragma unroll
            for (int r = 0; r < 4; ++r) {
                const float4 hv = *((const float4*)(hs + r * F_OUT + oh * 64) + it);
                acc[r] = fmaf(hv.x, av.x, acc[r]);
                acc[r] = fmaf(hv.y, av.y, acc[r]);
                acc[r] = fmaf(hv.z, av.z, acc[r]);
                acc[r] = fmaf(hv.w, av.w, acc[r]);
            }
        }
        __syncthreads();                    // red free (h combine done)
        #pragma unroll
        for (int r = 0; r < 4; ++r) red[oh][r][kh2] = acc[r];
    }
    __syncthreads();
    #pragma unroll
    for (int t = 0; t < 2; ++t) {
        const int idx = tid + t * 256;      // 512 = 4 rows x 128 kh2
        const int r = idx >> 7, kh2 = idx & 127;
        const float v = red[0][r][kh2] + red[1][r][kh2];
        if (kh2 < 64) hi[((size_t)row0 + r) * HH + kh2] = v + b1[kh2];
        else          hjs[r * HH + (kh2 - 64)] = v;
    }
    __syncthreads();
    {   // transposed store hjT[b][k][nl0 + rr]
        const int kk = tid >> 2, rr = tid & 3;
        hjT[((size_t)b * HH + kk) * NN + nl0 + rr] = hjs[rr * HH + kk];
    }
}

// ============================================================================
// K2: fused scores + exp + aggregation (unscaled) + per-block softmax stats.
// Block = 8 i-rows x 256 j (one j-half). 512 blocks x 512 threads.
//   y_blk[r][o] = sum_{j in half} exp(e[r][j] - m_blk) * h[j][o]
// ============================================================================
__global__ __launch_bounds__(512, 2) void k_score_agg(
    const float* __restrict__ hi, const float* __restrict__ hjT,
    const float* __restrict__ A2, const float* __restrict__ b2,
    const float* __restrict__ adj, const float* __restrict__ h,
    float* __restrict__ y, float* __restrict__ stat_m, float* __restrict__ stat_s)
{
    const int blk   = blockIdx.x;        // b*128 + itile*2 + jh
    const int b     = blk >> 7;
    const int itile = (blk >> 1) & 63;
    const int jh    = blk & 1;
    const int i0    = itile * 8;
    const int tid   = threadIdx.x;
    const int jt    = tid & 255;         // local j
    const int rh    = tid >> 8;          // row-half: rows rh*4 .. rh*4+3
    const int j     = jh * 256 + jt;

    __shared__ float hib[8 * HH];           // 2 KB   (hi + b1)
    __shared__ float a2s[HH];
    __shared__ float e_lds[256][12];        // 12 KB  (exp'd weights, padded)
    __shared__ float red[4][8][F_OUT];      // 16 KB
    __shared__ float rtmp[16];

    hib[tid < 512 ? tid : 0] = hi[((size_t)b * NN + i0) * HH + tid];
    if (tid < HH) a2s[tid] = A2[tid];
    __syncthreads();

    // ---- scores for 4 rows x column j ----
    float s4[4] = {0, 0, 0, 0};
    const float* hjb = hjT + (size_t)b * HH * NN + j;
    #pragma unroll 4
    for (int k4 = 0; k4 < 16; ++k4) {
        const float hj0 = hjb[(size_t)(k4 * 4 + 0) * NN];
        const float hj1 = hjb[(size_t)(k4 * 4 + 1) * NN];
        const float hj2 = hjb[(size_t)(k4 * 4 + 2) * NN];
        const float hj3 = hjb[(size_t)(k4 * 4 + 3) * NN];
        const float4 a2v = *(const float4*)(a2s + k4 * 4);
        #pragma unroll
        for (int r = 0; r < 4; ++r) {
            const float4 hv = *(const float4*)(hib + (rh * 4 + r) * HH + k4 * 4);
            s4[r] = fmaf(fmaxf(hv.x + hj0, 0.0f), a2v.x, s4[r]);
            s4[r] = fmaf(fmaxf(hv.y + hj1, 0.0f), a2v.y, s4[r]);
            s4[r] = fmaf(fmaxf(hv.z + hj2, 0.0f), a2v.z, s4[r]);
            s4[r] = fmaf(fmaxf(hv.w + hj3, 0.0f), a2v.w, s4[r]);
        }
    }

    const float b2v = b2[0];
    float lmax = -INFINITY;
    #pragma unroll
    for (int r = 0; r < 4; ++r) {
        float v = s4[r] + b2v;
        v = (v >= 0.0f) ? v : LALPHA * v;
        const float a = adj[((size_t)b * NN + i0 + rh * 4 + r) * NN + j];
        v = (a != 0.0f) ? v : NEG_INF_F;
        s4[r] = v;
        lmax = fmaxf(lmax, v);
    }

    // ---- block max ----
    #pragma unroll
    for (int off = 32; off; off >>= 1) lmax = fmaxf(lmax, __shfl_xor(lmax, off, 64));
    if ((tid & 63) == 0) rtmp[tid >> 6] = lmax;
    __syncthreads();
    float m_blk = rtmp[0];
    #pragma unroll
    for (int w = 1; w < 8; ++w) m_blk = fmaxf(m_blk, rtmp[w]);

    // ---- exp -> LDS, block sum ----
    float4 w4;
    w4.x = expf(s4[0] - m_blk);
    w4.y = expf(s4[1] - m_blk);
    w4.z = expf(s4[2] - m_blk);
    w4.w = expf(s4[3] - m_blk);
    *(float4*)(&e_lds[jt][rh * 4]) = w4;
    float ls = w4.x + w4.y + w4.z + w4.w;
    #pragma unroll
    for (int off = 32; off; off >>= 1) ls += __shfl_xor(ls, off, 64);
    if ((tid & 63) == 0) rtmp[8 + (tid >> 6)] = ls;
    __syncthreads();
    if (tid == 0) {
        stat_m[blk] = m_blk;
        float ssum = 0.0f;
        #pragma unroll
        for (int w = 0; w < 8; ++w) ssum += rtmp[8 + w];
        stat_s[blk] = ssum;
    }

    // ---- aggregate: y += w * h over this block's 256 j ----
    {
        const int o = tid & 127;
        const int p = tid >> 7;          // 4-way j split
        float acc[8] = {0, 0, 0, 0, 0, 0, 0, 0};
        const float* hb = h + (size_t)b * NN * F_OUT;
        #pragma unroll 4
        for (int q = 0; q < 64; ++q) {
            const int jl = p * 64 + q;
            const float hv = hb[(size_t)(jh * 256 + jl) * F_OUT + o];
            const float4 w0 = *(const float4*)&e_lds[jl][0];
            const float4 w1 = *(const float4*)&e_lds[jl][4];
            acc[0] = fmaf(w0.x, hv, acc[0]);
            acc[1] = fmaf(w0.y, hv, acc[1]);
            acc[2] = fmaf(w0.z, hv, acc[2]);
            acc[3] = fmaf(w0.w, hv, acc[3]);
            acc[4] = fmaf(w1.x, hv, acc[4]);
            acc[5] = fmaf(w1.y, hv, acc[5]);
            acc[6] = fmaf(w1.z, hv, acc[6]);
            acc[7] = fmaf(w1.w, hv, acc[7]);
        }
        #pragma unroll
        for (int r = 0; r < 8; ++r) red[p][r][o] = acc[r];
    }
    __syncthreads();
    #pragma unroll
    for (int t = 0; t < 2; ++t) {
        const int idx = tid + t * 512;   // 1024 = 8 rows x 128 o
        const int r = idx >> 7, oo = idx & 127;
        y[(size_t)blk * 1024 + idx] =
            red[0][r][oo] + red[1][r][oo] + red[2][r][oo] + red[3][r][oo];
    }
}

// ============================================================================
// K3: global M,S per batch (redundant per block) + combine halves + elu
// 256 blocks x 256 threads, 1024 outputs each
// ============================================================================
__global__ __launch_bounds__(256) void k_finish(
    const float* __restrict__ y, const float* __restrict__ stat_m,
    const float* __restrict__ stat_s, float* __restrict__ out)
{
    const int blk   = blockIdx.x;       // b*64 + itile
    const int b     = blk >> 6;
    const int itile = blk & 63;
    const int tid   = threadIdx.x;

    __shared__ float sm[4], ss[4];

    const float m = (tid < 128) ? stat_m[b * 128 + tid] : -INFINITY;
    float lm = m;
    #pragma unroll
    for (int off = 32; off; off >>= 1) lm = fmaxf(lm, __shfl_xor(lm, off, 64));
    if ((tid & 63) == 0) sm[tid >> 6] = lm;
    __syncthreads();
    const float M = fmaxf(fmaxf(sm[0], sm[1]), fmaxf(sm[2], sm[3]));

    float sv = (tid < 128) ? stat_s[b * 128 + tid] * expf(m - M) : 0.0f;
    #pragma unroll
    for (int off = 32; off; off >>= 1) sv += __shfl_xor(sv, off, 64);
    if ((tid & 63) == 0) ss[tid >> 6] = sv;
    __syncthreads();
    const float invS = 1.0f / (ss[0] + ss[1] + ss[2] + ss[3]);

    const float sc0 = expf(stat_m[b * 128 + itile * 2 + 0] - M) * invS;
    const float sc1 = expf(stat_m[b * 128 + itile * 2 + 1] - M) * invS;
    const float* y0 = y + (size_t)(b * 128 + itile * 2 + 0) * 1024;
    const float* y1 = y0 + 1024;
    float* ob = out + ((size_t)b * NN + itile * 8) * F_OUT;

    #pragma unroll
    for (int t = 0; t < 4; ++t) {
        const int idx = tid + t * 256;
        const float v = y0[idx] * sc0 + y1[idx] * sc1;
        ob[idx] = (v > 0.0f) ? v : expm1f(v);
    }
}

extern "C" void kernel_launch(void* const* d_in, const int* in_sizes, int n_in,
                              void* d_out, int out_size, void* d_ws, size_t ws_size,
                              hipStream_t stream) {
    const float* x   = (const float*)d_in[0];
    const float* adj = (const float*)d_in[1];
    const float* W   = (const float*)d_in[2];
    const float* bW  = (const float*)d_in[3];
    const float* A1  = (const float*)d_in[4];
    const float* b1  = (const float*)d_in[5];
    const float* A2  = (const float*)d_in[6];
    const float* b2  = (const float*)d_in[7];
    float* out = (float*)d_out;

    float* ws = (float*)d_ws;
    float* h      = ws;                                   // B*N*F_OUT = 262144
    float* hi     = h   + (size_t)BB * NN * F_OUT;        // B*N*H     = 131072
    float* hjT    = hi  + (size_t)BB * NN * HH;           // B*H*N     = 131072
    float* y      = hjT + (size_t)BB * HH * NN;           // 512*1024  = 524288
    float* stat_m = y   + (size_t)512 * 1024;             // 512
    float* stat_s = stat_m + 512;                         // 512

    k_proj     <<<BB * 128, 256, 0, stream>>>(x, W, bW, A1, b1, h, hi, hjT);
    k_score_agg<<<BB * 128, 512, 0, stream>>>(hi, hjT, A2, b2, adj, h, y, stat_m, stat_s);
    k_finish   <<<BB * 64,  256, 0, stream>>>(y, stat_m, stat_s, out);
}